// Round 7
// baseline (334.493 us; speedup 1.0000x reference)
//
#include <hip/hip_runtime.h>

// NCC loss: 1 - mean( cross^2 / (pvar*tvar + 1e-8) ) over 9^3 zero-padded
// box windows, input (4,1,160,160,160) fp32.
//
// R12: R11 validated occupancy-as-cap (25->51%, BW 2.7->3.2 TB/s) but its
// global re-read of z-9 doubled HBM fetch (evicted from cache) -> net loss.
// R12 keeps the on-chip ring but HALVES per-thread ownership: 2 cols/thread
// instead of 4. Ring 72->36 floats; ~80 regs/wave -> 6 waves/SIMD.
// Geometry: row=tid>>4, g=tid&15 (g<12 active: 12 col-pair groups cover the
// 24-col halo), 6 staging waves (384 slots, 288 active) + 1 dedicated
// reduction wave = BLK 448, launch_bounds(448,6) -> 3 blocks x 7 waves =
// ~21 waves/CU (vs R9's ~8). x-prefix for 2-col groups: lane m<8 produces
// outputs 2m,2m+1 = G(m)+G(m+1)+G(m+2)+G(m+3)+p0(m+4) and
// (G(m)-p0(m))+...+G(m+4), via uniform DPP shl1..shl4 (max source lane 11,
// no 16-lane DPP-row crossing). Depth-1 prefetch, one barrier/step,
// double-buffered s2, reduction protocol unchanged from R9.
// Spill tripwire: WRITE_SIZE must stay ~50KB.

#define DSZ    160
#define NBATCH 4
#define RAD    4
#define TX     16
#define TY     16
#define ZCHUNK 40
#define SLICE  (DSZ*DSZ)
#define VOL    (DSZ*DSZ*DSZ)
#define WINV   (1.0f/729.0f)
#define NVOX_INV (1.0f/16384000.0f)

#define NROW 24        // halo rows per tile
#define BLK  448       // 6 staging waves (row=tid>>4, g=tid&15, g<12) + 1 reduction wave

#define S2_RS 20                 // row stride: 16 outputs + pad (2-way banks)
#define S2_FS (NROW*S2_RS)       // 480 floats per field
#define S2_BUF (5*S2_FS)         // 2400 floats per parity buffer

__device__ __forceinline__ float dpp_shl1(float x) {  // lane i <- lane i+1 (16-lane row, OOB=0)
    return __int_as_float(__builtin_amdgcn_update_dpp(0, __float_as_int(x), 0x101, 0xf, 0xf, true));
}
__device__ __forceinline__ float dpp_shl2(float x) {  // lane i <- lane i+2
    return __int_as_float(__builtin_amdgcn_update_dpp(0, __float_as_int(x), 0x102, 0xf, 0xf, true));
}
__device__ __forceinline__ float dpp_shl3(float x) {  // lane i <- lane i+3
    return __int_as_float(__builtin_amdgcn_update_dpp(0, __float_as_int(x), 0x103, 0xf, 0xf, true));
}
__device__ __forceinline__ float dpp_shl4(float x) {  // lane i <- lane i+4
    return __int_as_float(__builtin_amdgcn_update_dpp(0, __float_as_int(x), 0x104, 0xf, 0xf, true));
}

__global__ __launch_bounds__(BLK, 6)
void ncc_main(const float* __restrict__ pred, const float* __restrict__ tgt,
              float* __restrict__ accum)
{
    const int tid = threadIdx.x;
    const int row = tid >> 4;      // 0..27 (staging uses 0..23)
    const int g   = tid & 15;      // col-pair group; g<12 active
    const int ox  = blockIdx.x * TX;
    const int oy  = blockIdx.y * TY;
    const int batch = blockIdx.z >> 2;
    const int z0  = (blockIdx.z & 3) * ZCHUNK;

    __shared__ float s2[2*S2_BUF];   // 19.2 KB, double-buffered [f][y][x pad20]

    const bool stg = (tid < 384) && (g < 12);
    const bool red = (tid >= 384);               // dedicated reduction wave
    const int  gy  = oy - RAD + row;
    const int  gx0 = ox - RAD + g*2;             // 2 halo cols per thread
    const bool ldok = stg && (gy >= 0) && (gy < DSZ) && (gx0 >= 0) && (gx0 + 1 < DSZ);
    const int  base = batch*VOL + gy*DSZ + gx0;  // only used under ldok

    // register ring of raw slice values (own 2 columns), chunk-local slots
    float rp[9][2], rt[9][2];
    float zs[5][2];
    #pragma unroll
    for (int k = 0; k < 9; ++k) {
        rp[k][0] = 0.f; rp[k][1] = 0.f;
        rt[k][0] = 0.f; rt[k][1] = 0.f;
    }
    #pragma unroll
    for (int f = 0; f < 5; ++f) { zs[f][0] = 0.f; zs[f][1] = 0.f; }

    // ---- warm-up: chunk-local slices 0..7 (z = z0-4 .. z0+3) -> slots 0..7
    if (stg) {
        #pragma unroll
        for (int i = 0; i < 8; ++i) {
            int z = z0 - RAD + i;
            if (z >= 0) {                       // uniform; z < DSZ always here
                float2 p2 = {0,0}, t2 = {0,0};
                if (ldok) {
                    p2 = *(const float2*)(pred + base + z*SLICE);
                    t2 = *(const float2*)(tgt  + base + z*SLICE);
                }
                const float pc[2] = {p2.x, p2.y};
                const float tc[2] = {t2.x, t2.y};
                #pragma unroll
                for (int j = 0; j < 2; ++j) {
                    zs[0][j] += pc[j];        zs[1][j] += tc[j];
                    zs[2][j] += pc[j]*pc[j];  zs[3][j] += tc[j]*tc[j];
                    zs[4][j] += pc[j]*tc[j];
                    rp[i][j] = pc[j];  rt[i][j] = tc[j];
                }
            }
        }
    }

    // ---- streaming prefetch of the next add-slice (depth 1) ----
    int za = z0 + RAD;                      // absolute z of next fetch
    int zmax = z0 + ZCHUNK + RAD;           // last useful slice + 1
    if (zmax > DSZ) zmax = DSZ;
    float2 pa2 = {0,0}, ta2 = {0,0};

#define PF_NEXT() do {                                                        \
    float2 _p = {0,0}, _t = {0,0};                                            \
    if (ldok && za < zmax) {                                                  \
        _p = *(const float2*)(pred + base + za*SLICE);                        \
        _t = *(const float2*)(tgt  + base + za*SLICE);                        \
    }                                                                         \
    pa2 = _p; ta2 = _t; ++za;                                                 \
} while (0)

    if (stg) PF_NEXT();  // slice for step 0

    int pb = 1;          // parity buffer toggle (first step -> 0)
    float acc = 0.f;

#define NCC_STEP(SLOT) do {                                                   \
    pb ^= 1;                                                                  \
    float* s2w = s2 + pb*S2_BUF;                                              \
    if (stg) {                                                                \
        const float pc0 = pa2.x, pc1 = pa2.y;                                 \
        const float tc0 = ta2.x, tc1 = ta2.y;                                 \
        PF_NEXT();  /* issue slice s+1; full step to complete */              \
        {                                                                     \
            float ps = rp[SLOT][0], qs = rt[SLOT][0];                         \
            float d0 = pc0 - ps, d1 = tc0 - qs;                               \
            zs[0][0] += d0;                    zs[1][0] += d1;                \
            zs[2][0] += d0*(pc0 + ps);         zs[3][0] += d1*(tc0 + qs);     \
            zs[4][0] += pc0*tc0 - ps*qs;                                      \
            rp[SLOT][0] = pc0;  rt[SLOT][0] = tc0;                            \
        }                                                                     \
        {                                                                     \
            float ps = rp[SLOT][1], qs = rt[SLOT][1];                         \
            float d0 = pc1 - ps, d1 = tc1 - qs;                               \
            zs[0][1] += d0;                    zs[1][1] += d1;                \
            zs[2][1] += d0*(pc1 + ps);         zs[3][1] += d1*(tc1 + qs);     \
            zs[4][1] += pc1*tc1 - ps*qs;                                      \
            rp[SLOT][1] = pc1;  rt[SLOT][1] = tc1;                            \
        }                                                                     \
        _Pragma("unroll")                                                     \
        for (int f = 0; f < 5; ++f) {                                         \
            float v0 = zs[f][0];                                              \
            float G  = v0 + zs[f][1];          /* 2-col group sum */          \
            float G1 = dpp_shl1(G);                                           \
            float G2 = dpp_shl2(G);                                           \
            float G3 = dpp_shl3(G);                                           \
            float A0 = dpp_shl4(v0);           /* p0(m+4) */                  \
            float A1 = dpp_shl4(G);            /* G(m+4)  */                  \
            if (g < 8) {                                                      \
                float s = G + G1 + G2 + G3;    /* cols 2m..2m+7 */            \
                float2 o;                                                     \
                o.x = s + A0;                  /* + col 2m+8            */    \
                o.y = s - v0 + A1;             /* - col 2m + cols 2m+8,9 */   \
                *(float2*)&s2w[f*S2_FS + row*S2_RS + 2*g] = o;                \
            }                                                                 \
        }                                                                     \
    }                                                                         \
    __syncthreads();                                                          \
    if (red) {                                                                \
        const int x = tid & 15, yq = ((tid >> 4) & 3)*4;                      \
        float S[5][4];                                                        \
        _Pragma("unroll")                                                     \
        for (int f = 0; f < 5; ++f) {                                         \
            const float* col = &s2w[f*S2_FS + x];                             \
            float r0 = col[(yq+0)*S2_RS], r1 = col[(yq+1)*S2_RS];             \
            float r2 = col[(yq+2)*S2_RS], r3 = col[(yq+3)*S2_RS];             \
            float run = r0+r1+r2+r3 + col[(yq+4)*S2_RS] + col[(yq+5)*S2_RS]   \
                      + col[(yq+6)*S2_RS] + col[(yq+7)*S2_RS];                \
            run += col[(yq+8)*S2_RS];        S[f][0] = run;                   \
            run += col[(yq+9)*S2_RS]  - r0;  S[f][1] = run;                   \
            run += col[(yq+10)*S2_RS] - r1;  S[f][2] = run;                   \
            run += col[(yq+11)*S2_RS] - r2;  S[f][3] = run;                   \
        }                                                                     \
        _Pragma("unroll")                                                     \
        for (int i = 0; i < 4; ++i) {                                         \
            float Sp = S[0][i], St = S[1][i];                                 \
            float cross = S[4][i] - Sp*St*WINV;                               \
            float pv    = S[2][i] - Sp*Sp*WINV;                               \
            float tv    = S[3][i] - St*St*WINV;                               \
            acc += cross*cross / (pv*tv + 1e-8f);                             \
        }                                                                     \
    }                                                                         \
} while (0)

    // steps s=0..3: slots (s+8)%9 = 8,0,1,2
    NCC_STEP(8); NCC_STEP(0); NCC_STEP(1); NCC_STEP(2);
    // steps s=4..39: slot sequence (s+8)%9 is 9-periodic: 3,4,5,6,7,8,0,1,2
    for (int it = 0; it < 4; ++it) {
        NCC_STEP(3); NCC_STEP(4); NCC_STEP(5);
        NCC_STEP(6); NCC_STEP(7); NCC_STEP(8);
        NCC_STEP(0); NCC_STEP(1); NCC_STEP(2);
    }
#undef NCC_STEP
#undef PF_NEXT

    // all cc partials live in the reduction wave (tid 384..447)
    if (red) {
        float v = acc;
        #pragma unroll
        for (int off = 32; off > 0; off >>= 1) v += __shfl_down(v, off, 64);
        if (tid == 384) atomicAdd(accum, v);
    }
}

__global__ void ncc_final(const float* __restrict__ accum, float* __restrict__ out)
{
    out[0] = 1.0f - accum[0] * NVOX_INV;
}

extern "C" void kernel_launch(void* const* d_in, const int* in_sizes, int n_in,
                              void* d_out, int out_size, void* d_ws, size_t ws_size,
                              hipStream_t stream)
{
    const float* pred = (const float*)d_in[0];
    const float* tgt  = (const float*)d_in[1];
    float* out = (float*)d_out;
    float* ws  = (float*)d_ws;

    hipMemsetAsync(ws, 0, sizeof(float), stream);
    dim3 grid(DSZ/TX, DSZ/TY, NBATCH*4);   // 10 x 10 x 16 = 1600 blocks
    ncc_main<<<grid, BLK, 0, stream>>>(pred, tgt, ws);
    ncc_final<<<1, 1, 0, stream>>>(ws, out);
}

// Round 8
// 250.414 us; speedup vs baseline: 1.3358x; 1.3358x over previous
//
#include <hip/hip_runtime.h>

// NCC loss: 1 - mean( cross^2 / (pvar*tvar + 1e-8) ) over 9^3 zero-padded
// box windows, input (4,1,160,160,160) fp32.
//
// R13: R12's tripwire fired — launch_bounds(448,6) forced an ~85-reg budget
// and the allocator SPILLED (WRITE_SIZE 195MB) rather than fit ring+temps;
// occupancy still hit 47%, proving the 2-col geometry works and TLP responds.
// R13 = R12's verified staging (2 cols/thread, 36-float ring, DPP shl1..4
// prefix) with the budget relaxed and the block rounded out:
//   - launch_bounds(512,4): 128 regs/wave budget, footprint ~80-90 -> no
//     spill, slack for the scheduler.
//   - BLK 512 = 6 staging waves (tid<384, g<12) + TWO reduction waves
//     (128 thr x 2 outputs, halves the reduce critical path R9 exposed).
//   - 8 waves/block x 4/SIMD = exactly 2 blocks/CU, 16 waves/CU, zero
//     residency-granularity waste (R9: ~12 waves/CU).
// Depth-1 prefetch kept: __syncthreads drains vmcnt(0) anyway, so deeper
// prefetch buys nothing (R6-R8 evidence). LDS 19.2 KB unchanged.
// Spill tripwire: WRITE_SIZE must stay ~50KB.

#define DSZ    160
#define NBATCH 4
#define RAD    4
#define TX     16
#define TY     16
#define ZCHUNK 40
#define SLICE  (DSZ*DSZ)
#define VOL    (DSZ*DSZ*DSZ)
#define WINV   (1.0f/729.0f)
#define NVOX_INV (1.0f/16384000.0f)

#define NROW 24        // halo rows per tile
#define BLK  512       // 6 staging waves + 2 reduction waves

#define S2_RS 20                 // row stride: 16 outputs + pad (2-way banks)
#define S2_FS (NROW*S2_RS)       // 480 floats per field
#define S2_BUF (5*S2_FS)         // 2400 floats per parity buffer

__device__ __forceinline__ float dpp_shl1(float x) {  // lane i <- lane i+1 (16-lane row, OOB=0)
    return __int_as_float(__builtin_amdgcn_update_dpp(0, __float_as_int(x), 0x101, 0xf, 0xf, true));
}
__device__ __forceinline__ float dpp_shl2(float x) {  // lane i <- lane i+2
    return __int_as_float(__builtin_amdgcn_update_dpp(0, __float_as_int(x), 0x102, 0xf, 0xf, true));
}
__device__ __forceinline__ float dpp_shl3(float x) {  // lane i <- lane i+3
    return __int_as_float(__builtin_amdgcn_update_dpp(0, __float_as_int(x), 0x103, 0xf, 0xf, true));
}
__device__ __forceinline__ float dpp_shl4(float x) {  // lane i <- lane i+4
    return __int_as_float(__builtin_amdgcn_update_dpp(0, __float_as_int(x), 0x104, 0xf, 0xf, true));
}

__global__ __launch_bounds__(BLK, 4)
void ncc_main(const float* __restrict__ pred, const float* __restrict__ tgt,
              float* __restrict__ accum)
{
    const int tid = threadIdx.x;
    const int row = tid >> 4;      // 0..31 (staging uses 0..23)
    const int g   = tid & 15;      // col-pair group; g<12 active
    const int ox  = blockIdx.x * TX;
    const int oy  = blockIdx.y * TY;
    const int batch = blockIdx.z >> 2;
    const int z0  = (blockIdx.z & 3) * ZCHUNK;

    __shared__ float s2[2*S2_BUF];   // 19.2 KB, double-buffered [f][y][x pad20]

    const bool stg = (tid < 384) && (g < 12);
    const bool red = (tid >= 384);               // two dedicated reduction waves
    const int  gy  = oy - RAD + row;
    const int  gx0 = ox - RAD + g*2;             // 2 halo cols per thread
    const bool ldok = stg && (gy >= 0) && (gy < DSZ) && (gx0 >= 0) && (gx0 + 1 < DSZ);
    const int  base = batch*VOL + gy*DSZ + gx0;  // only used under ldok

    // register ring of raw slice values (own 2 columns), chunk-local slots
    float rp[9][2], rt[9][2];
    float zs[5][2];
    #pragma unroll
    for (int k = 0; k < 9; ++k) {
        rp[k][0] = 0.f; rp[k][1] = 0.f;
        rt[k][0] = 0.f; rt[k][1] = 0.f;
    }
    #pragma unroll
    for (int f = 0; f < 5; ++f) { zs[f][0] = 0.f; zs[f][1] = 0.f; }

    // ---- warm-up: chunk-local slices 0..7 (z = z0-4 .. z0+3) -> slots 0..7
    if (stg) {
        #pragma unroll
        for (int i = 0; i < 8; ++i) {
            int z = z0 - RAD + i;
            if (z >= 0) {                       // uniform; z < DSZ always here
                float2 p2 = {0,0}, t2 = {0,0};
                if (ldok) {
                    p2 = *(const float2*)(pred + base + z*SLICE);
                    t2 = *(const float2*)(tgt  + base + z*SLICE);
                }
                const float pc[2] = {p2.x, p2.y};
                const float tc[2] = {t2.x, t2.y};
                #pragma unroll
                for (int j = 0; j < 2; ++j) {
                    zs[0][j] += pc[j];        zs[1][j] += tc[j];
                    zs[2][j] += pc[j]*pc[j];  zs[3][j] += tc[j]*tc[j];
                    zs[4][j] += pc[j]*tc[j];
                    rp[i][j] = pc[j];  rt[i][j] = tc[j];
                }
            }
        }
    }

    // ---- streaming prefetch of the next add-slice (depth 1) ----
    int za = z0 + RAD;                      // absolute z of next fetch
    int zmax = z0 + ZCHUNK + RAD;           // last useful slice + 1
    if (zmax > DSZ) zmax = DSZ;
    float2 pa2 = {0,0}, ta2 = {0,0};

#define PF_NEXT() do {                                                        \
    float2 _p = {0,0}, _t = {0,0};                                            \
    if (ldok && za < zmax) {                                                  \
        _p = *(const float2*)(pred + base + za*SLICE);                        \
        _t = *(const float2*)(tgt  + base + za*SLICE);                        \
    }                                                                         \
    pa2 = _p; ta2 = _t; ++za;                                                 \
} while (0)

    if (stg) PF_NEXT();  // slice for step 0

    int pb = 1;          // parity buffer toggle (first step -> 0)
    float acc = 0.f;

#define NCC_STEP(SLOT) do {                                                   \
    pb ^= 1;                                                                  \
    float* s2w = s2 + pb*S2_BUF;                                              \
    if (stg) {                                                                \
        const float pc0 = pa2.x, pc1 = pa2.y;                                 \
        const float tc0 = ta2.x, tc1 = ta2.y;                                 \
        PF_NEXT();  /* issue slice s+1; full step to complete */              \
        {                                                                     \
            float ps = rp[SLOT][0], qs = rt[SLOT][0];                         \
            float d0 = pc0 - ps, d1 = tc0 - qs;                               \
            zs[0][0] += d0;                    zs[1][0] += d1;                \
            zs[2][0] += d0*(pc0 + ps);         zs[3][0] += d1*(tc0 + qs);     \
            zs[4][0] += pc0*tc0 - ps*qs;                                      \
            rp[SLOT][0] = pc0;  rt[SLOT][0] = tc0;                            \
        }                                                                     \
        {                                                                     \
            float ps = rp[SLOT][1], qs = rt[SLOT][1];                         \
            float d0 = pc1 - ps, d1 = tc1 - qs;                               \
            zs[0][1] += d0;                    zs[1][1] += d1;                \
            zs[2][1] += d0*(pc1 + ps);         zs[3][1] += d1*(tc1 + qs);     \
            zs[4][1] += pc1*tc1 - ps*qs;                                      \
            rp[SLOT][1] = pc1;  rt[SLOT][1] = tc1;                            \
        }                                                                     \
        _Pragma("unroll")                                                     \
        for (int f = 0; f < 5; ++f) {                                         \
            float v0 = zs[f][0];                                              \
            float G  = v0 + zs[f][1];          /* 2-col group sum */          \
            float G1 = dpp_shl1(G);                                           \
            float G2 = dpp_shl2(G);                                           \
            float G3 = dpp_shl3(G);                                           \
            float A0 = dpp_shl4(v0);           /* p0(m+4) */                  \
            float A1 = dpp_shl4(G);            /* G(m+4)  */                  \
            if (g < 8) {                                                      \
                float s = G + G1 + G2 + G3;    /* cols 2m..2m+7 */            \
                float2 o;                                                     \
                o.x = s + A0;                  /* + col 2m+8            */    \
                o.y = s - v0 + A1;             /* - col 2m + cols 2m+8,9 */   \
                *(float2*)&s2w[f*S2_FS + row*S2_RS + 2*g] = o;                \
            }                                                                 \
        }                                                                     \
    }                                                                         \
    __syncthreads();                                                          \
    if (red) {                                                                \
        const int x = tid & 15, yq = ((tid >> 4) & 7)*2;                      \
        float S[5][2];                                                        \
        _Pragma("unroll")                                                     \
        for (int f = 0; f < 5; ++f) {                                         \
            const float* col = &s2w[f*S2_FS + x];                             \
            float r0 = col[(yq+0)*S2_RS];                                     \
            float run = r0 + col[(yq+1)*S2_RS] + col[(yq+2)*S2_RS]            \
                      + col[(yq+3)*S2_RS] + col[(yq+4)*S2_RS]                 \
                      + col[(yq+5)*S2_RS] + col[(yq+6)*S2_RS]                 \
                      + col[(yq+7)*S2_RS] + col[(yq+8)*S2_RS];                \
            S[f][0] = run;                                                    \
            run += col[(yq+9)*S2_RS] - r0;  S[f][1] = run;                    \
        }                                                                     \
        _Pragma("unroll")                                                     \
        for (int i = 0; i < 2; ++i) {                                         \
            float Sp = S[0][i], St = S[1][i];                                 \
            float cross = S[4][i] - Sp*St*WINV;                               \
            float pv    = S[2][i] - Sp*Sp*WINV;                               \
            float tv    = S[3][i] - St*St*WINV;                               \
            acc += cross*cross / (pv*tv + 1e-8f);                             \
        }                                                                     \
    }                                                                         \
} while (0)

    // steps s=0..3: slots (s+8)%9 = 8,0,1,2
    NCC_STEP(8); NCC_STEP(0); NCC_STEP(1); NCC_STEP(2);
    // steps s=4..39: slot sequence (s+8)%9 is 9-periodic: 3,4,5,6,7,8,0,1,2
    for (int it = 0; it < 4; ++it) {
        NCC_STEP(3); NCC_STEP(4); NCC_STEP(5);
        NCC_STEP(6); NCC_STEP(7); NCC_STEP(8);
        NCC_STEP(0); NCC_STEP(1); NCC_STEP(2);
    }
#undef NCC_STEP
#undef PF_NEXT

    // cc partials live in the two reduction waves (tid 384..511)
    if (red) {
        float v = acc;
        #pragma unroll
        for (int off = 32; off > 0; off >>= 1) v += __shfl_down(v, off, 64);
        if ((tid & 63) == 0) atomicAdd(accum, v);
    }
}

__global__ void ncc_final(const float* __restrict__ accum, float* __restrict__ out)
{
    out[0] = 1.0f - accum[0] * NVOX_INV;
}

extern "C" void kernel_launch(void* const* d_in, const int* in_sizes, int n_in,
                              void* d_out, int out_size, void* d_ws, size_t ws_size,
                              hipStream_t stream)
{
    const float* pred = (const float*)d_in[0];
    const float* tgt  = (const float*)d_in[1];
    float* out = (float*)d_out;
    float* ws  = (float*)d_ws;

    hipMemsetAsync(ws, 0, sizeof(float), stream);
    dim3 grid(DSZ/TX, DSZ/TY, NBATCH*4);   // 10 x 10 x 16 = 1600 blocks
    ncc_main<<<grid, BLK, 0, stream>>>(pred, tgt, ws);
    ncc_final<<<1, 1, 0, stream>>>(ws, out);
}